// Round 13
// baseline (309.916 us; speedup 1.0000x reference)
//
#include <hip/hip_runtime.h>
#include <stdint.h>

typedef unsigned short u16;
typedef __attribute__((ext_vector_type(8))) short short8;
typedef __attribute__((ext_vector_type(4))) float f32x4;
typedef __attribute__((ext_vector_type(8))) u16 u16x8;
typedef __attribute__((ext_vector_type(4))) u16 u16x4;

__device__ __forceinline__ u16 f2bf(float f) {
  union { float f; uint32_t u; } v; v.f = f;
  uint32_t u = v.u;
  uint32_t r = (u + 0x7FFFu + ((u >> 16) & 1u)) >> 16;
  return (u16)r;
}
__device__ __forceinline__ float bf2f(u16 b) {
  union { uint32_t u; float f; } v; v.u = ((uint32_t)b) << 16;
  return v.f;
}

__device__ __forceinline__ void gload16(const u16* g, u16* l) {
  __builtin_amdgcn_global_load_lds(
      (const __attribute__((address_space(1))) void*)g,
      (__attribute__((address_space(3))) void*)l, 16, 0, 0);
}

// C[r][c] = sum_k A[r][k] * Bt[c][k], bf16 in, fp32 accum.
// R13: 256x256 tile, BK=32, 512 thr = 8 waves (2M x 4N), per-wave 128x64.
// LDS = 2 dbuf x (A[256][32] + B[256][32]) bf16 = 64 KB. 1 block/CU.
// Never-drain boundary: compute(t) -> barrier_bot -> issue(t+2 into freed buf)
// -> s_waitcnt vmcnt(4) (own t+1 loads retired, in-order; t+2 stays in flight)
// -> barrier_top (cross-wave visibility) -> compute(t+1). Drain only at tail.
// R11 swizzle carried (slot ^= (row>>1)&3 on BOTH global source and ds_read;
// LDS dest linear per rule #21) -> 0 bank conflicts, bit-identical math.
// OMODE 0: +bias, bf16 store (QKV). 1: *scale, bf16 (QK^T). 2: f32 (PV->out).
template<int OMODE>
__global__ __launch_bounds__(512, 2) void gemm_bt(
    const u16* __restrict__ A, long long sAz,
    const u16* __restrict__ Bt, long long sBz,
    u16* __restrict__ C, float* __restrict__ Cf, long long sCz,
    const float* __restrict__ bias, float scale,
    int lda, int ldb, int ldc, int K)
{
  __shared__ __align__(16) u16 As[2][256 * 32];
  __shared__ __align__(16) u16 Bs[2][256 * 32];
  const int tid = threadIdx.x;
  const int w = tid >> 6, l = tid & 63;
  const int wm = w >> 2, wn = w & 3;          // 2 x 4 wave grid
  const int z = blockIdx.z;
  A  += sAz * z;
  Bt += sBz * z;
  const long long czoff = sCz * z;
  const long long bm = (long long)blockIdx.x * 256;
  const long long bn = (long long)blockIdx.y * 256;

  // staging: tile = 256 rows x 32 k = 16 KB = 1024 x 16B chunks; thread does
  // chunks {tid, tid+512}. chunk c: row = c>>2, source colgrp pre-swizzled
  // = (c&3) ^ ((c>>3)&3)  [(row>>1)&3 == (c>>3)&3].  LDS dest linear c*16B.
  const int c0 = tid, c1 = tid + 512;
  const int r0s = c0 >> 2, r1s = c1 >> 2;
  const int g0 = ((c0 & 3) ^ ((c0 >> 3) & 3)) * 8;
  const int g1 = ((c1 & 3) ^ ((c1 >> 3) & 3)) * 8;
  const u16* a0 = A  + (bm + r0s) * lda + g0;
  const u16* a1 = A  + (bm + r1s) * lda + g1;
  const u16* b0 = Bt + (bn + r0s) * ldb + g0;
  const u16* b1 = Bt + (bn + r1s) * ldb + g1;
  const int d0 = c0 * 8, d1 = c1 * 8;        // LDS elem offsets

  // read: logical kslice (l>>4) at row r -> physical slot ^ ((r>>1)&3);
  // row-dependent term is per-lane constant (all row strides are mult. of 16).
  const int slot = ((l >> 4) ^ (((l & 15) >> 1) & 3)) * 8;
  int a_off[8], b_off[4];
#pragma unroll
  for (int r = 0; r < 8; ++r)
    a_off[r] = (wm * 128 + r * 16 + (l & 15)) * 32 + slot;
#pragma unroll
  for (int c = 0; c < 4; ++c)
    b_off[c] = (wn * 64 + c * 16 + (l & 15)) * 32 + slot;

  const int nk = K >> 5;

  // prologue: stage tiles 0,1
  gload16(a0, &As[0][d0]); gload16(a1, &As[0][d1]);
  gload16(b0, &Bs[0][d0]); gload16(b1, &Bs[0][d1]);
  a0 += 32; a1 += 32; b0 += 32; b1 += 32;
  gload16(a0, &As[1][d0]); gload16(a1, &As[1][d1]);
  gload16(b0, &Bs[1][d0]); gload16(b1, &Bs[1][d1]);
  a0 += 32; a1 += 32; b0 += 32; b1 += 32;
  asm volatile("s_waitcnt vmcnt(4)" ::: "memory");   // own tile-0 loads done
  __builtin_amdgcn_s_barrier();                      // all waves' tile 0 visible
  __builtin_amdgcn_sched_barrier(0);

  f32x4 acc[8][4] = {};

  for (int t = 0; t < nk; ++t) {
    const int cb = t & 1;
    short8 bf[4], af[8];
#pragma unroll
    for (int c = 0; c < 4; ++c)
      bf[c] = *(const short8*)(&Bs[cb][b_off[c]]);
#pragma unroll
    for (int r = 0; r < 8; ++r)
      af[r] = *(const short8*)(&As[cb][a_off[r]]);
    __builtin_amdgcn_s_setprio(1);
#pragma unroll
    for (int r = 0; r < 8; ++r)
#pragma unroll
      for (int c = 0; c < 4; ++c)
        acc[r][c] = __builtin_amdgcn_mfma_f32_16x16x32_bf16(
            af[r], bf[c], acc[r][c], 0, 0, 0);
    __builtin_amdgcn_s_setprio(0);
    if (t + 1 == nk) break;
    __builtin_amdgcn_s_barrier();          // bot: all reads of buf cb done
    __builtin_amdgcn_sched_barrier(0);
    if (t + 2 < nk) {
      gload16(a0, &As[cb][d0]); gload16(a1, &As[cb][d1]);
      gload16(b0, &Bs[cb][d0]); gload16(b1, &Bs[cb][d1]);
      a0 += 32; a1 += 32; b0 += 32; b1 += 32;
      asm volatile("s_waitcnt vmcnt(4)" ::: "memory");  // t+1 retired, t+2 in flight
    } else {
      asm volatile("s_waitcnt vmcnt(0)" ::: "memory");  // tail only
    }
    __builtin_amdgcn_s_barrier();          // top: all waves' t+1 loads visible
    __builtin_amdgcn_sched_barrier(0);
  }

  // epilogue: D col = lane&15, row = (lane>>4)*4 + i  [oracle-verified R7]
#pragma unroll
  for (int r = 0; r < 8; ++r) {
#pragma unroll
    for (int c = 0; c < 4; ++c) {
      const long long rr = bm + wm * 128 + r * 16 + (l >> 4) * 4;
      const long long cc = bn + wn * 64 + c * 16 + (l & 15);
      float badd = 0.f;
      if (OMODE == 0) badd = bias[(long long)z * ldc + cc];
#pragma unroll
      for (int i = 0; i < 4; ++i) {
        float v = acc[r][c][i];
        if (OMODE == 0) v += badd;
        if (OMODE == 1) v *= scale;
        if (OMODE == 2)
          Cf[czoff + (rr + i) * ldc + cc] = v;        // f32 output
        else
          C[czoff + (rr + i) * ldc + cc] = f2bf(v);   // bf16 intermediate
      }
    }
  }
}

// f32 -> bf16, 4 elems/thread, grid-stride
__global__ __launch_bounds__(256) void cvt_f32_bf16(
    const float* __restrict__ src, u16* __restrict__ dst, int n4)
{
  int i = blockIdx.x * 256 + threadIdx.x;
  const int stride = gridDim.x * 256;
  for (; i < n4; i += stride) {
    f32x4 v = *(const f32x4*)(src + (long long)i * 4);
    u16x4 o;
    o[0] = f2bf(v[0]); o[1] = f2bf(v[1]);
    o[2] = f2bf(v[2]); o[3] = f2bf(v[3]);
    *(u16x4*)(dst + (long long)i * 4) = o;
  }
}

// vb [8][2048][768] bf16 -> vt [8][768][2048] bf16
__global__ void transpose_v(const u16* __restrict__ vb, u16* __restrict__ vt)
{
  __shared__ u16 tile[32][33];
  const int b = blockIdx.z;
  const int e0 = blockIdx.x * 32, m0 = blockIdx.y * 32;
  const int tx = threadIdx.x, ty = threadIdx.y;
  const u16* src = vb + ((long long)b * 2048 + m0) * 768 + e0;
#pragma unroll
  for (int i = 0; i < 4; ++i)
    tile[ty + i * 8][tx] = src[(ty + i * 8) * 768 + tx];
  __syncthreads();
  u16* dst = vt + ((long long)b * 768 + e0) * 2048 + m0;
#pragma unroll
  for (int i = 0; i < 4; ++i)
    dst[(ty + i * 8) * 2048 + tx] = tile[tx][ty + i * 8];
}

// W f32 [d][e] -> wt bf16 [z][e][d]
__global__ void prep_w(const float* __restrict__ Wq, const float* __restrict__ Wk,
                       const float* __restrict__ Wv, u16* __restrict__ wt)
{
  __shared__ float tile[32][33];
  const int zz = blockIdx.z;
  const float* W = zz == 0 ? Wq : (zz == 1 ? Wk : Wv);
  const int e0 = blockIdx.x * 32, d0 = blockIdx.y * 32;
  const int tx = threadIdx.x, ty = threadIdx.y;
#pragma unroll
  for (int i = 0; i < 4; ++i)
    tile[ty + i * 8][tx] = W[(long long)(d0 + ty + i * 8) * 768 + e0 + tx];
  __syncthreads();
  u16* dst = wt + (long long)zz * 768 * 768;
#pragma unroll
  for (int i = 0; i < 4; ++i)
    dst[(long long)(e0 + ty + i * 8) * 768 + d0 + tx] = f2bf(tile[tx][ty + i * 8]);
}

// biases f32: pack into contiguous [3][768]
__global__ void prep_b(const float* bq, const float* bk, const float* bv, float* dst)
{
  const int zz = blockIdx.x;
  const float* s = zz == 0 ? bq : (zz == 1 ? bk : bv);
  for (int i = threadIdx.x; i < 768; i += 256) dst[zz * 768 + i] = s[i];
}

// in-place row softmax on bf16 [rows][2048]; one block (256 thr) per row
__global__ __launch_bounds__(256) void softmax_rows(u16* __restrict__ p)
{
  const long long row = blockIdx.x;
  u16* r = p + row * 2048;
  const int t = threadIdx.x;
  const int l = t & 63, w = t >> 6;
  u16x8 vv = *(const u16x8*)(r + t * 8);
  float x[8];
#pragma unroll
  for (int i = 0; i < 8; ++i) x[i] = bf2f(vv[i]);
  float m = x[0];
#pragma unroll
  for (int i = 1; i < 8; ++i) m = fmaxf(m, x[i]);
#pragma unroll
  for (int off = 32; off >= 1; off >>= 1) m = fmaxf(m, __shfl_xor(m, off, 64));
  __shared__ float redm[4], reds[4];
  if (l == 0) redm[w] = m;
  __syncthreads();
  m = fmaxf(fmaxf(redm[0], redm[1]), fmaxf(redm[2], redm[3]));
  float s = 0.f;
#pragma unroll
  for (int i = 0; i < 8; ++i) { x[i] = expf(x[i] - m); s += x[i]; }
#pragma unroll
  for (int off = 32; off >= 1; off >>= 1) s += __shfl_xor(s, off, 64);
  if (l == 0) reds[w] = s;
  __syncthreads();
  s = reds[0] + reds[1] + reds[2] + reds[3];
  const float inv = 1.0f / s;
  u16x8 ov;
#pragma unroll
  for (int i = 0; i < 8; ++i) ov[i] = f2bf(x[i] * inv);
  *(u16x8*)(r + t * 8) = ov;
}

extern "C" void kernel_launch(void* const* d_in, const int* in_sizes, int n_in,
                              void* d_out, int out_size, void* d_ws, size_t ws_size,
                              hipStream_t stream)
{
  (void)in_sizes; (void)n_in; (void)out_size;
  const float* x  = (const float*)d_in[0];
  const float* Wq = (const float*)d_in[1];
  const float* bq = (const float*)d_in[2];
  const float* Wk = (const float*)d_in[3];
  const float* bk = (const float*)d_in[4];
  const float* Wv = (const float*)d_in[5];
  const float* bv = (const float*)d_in[6];
  float* out = (float*)d_out;   // reference output dtype = float32

  // ws layout (bytes): wt @0; qb @3538944; kb,vb follow; vt @79036416;
  // p @104202240 (xb aliased); wsb @171311104. total 171,320,320.
  const size_t NEEDED = 171320320;
  if (ws_size < NEEDED) return;

  char* ws = (char*)d_ws;
  u16* wt  = (u16*)ws;
  u16* qb  = (u16*)(ws + 3538944);
  u16* vt  = (u16*)(ws + 79036416);
  u16* p   = (u16*)(ws + 104202240);
  u16* xb  = p;  // alias: x(bf16) dead before QK^T writes p
  float* wsb = (float*)(ws + 171311104);
  u16* kb = qb + (long long)16384 * 768;
  u16* vb = kb + (long long)16384 * 768;

  cvt_f32_bf16<<<4096, 256, 0, stream>>>(x, xb, 3145728);
  prep_w<<<dim3(24, 24, 3), dim3(32, 8), 0, stream>>>(Wq, Wk, Wv, wt);
  prep_b<<<3, 256, 0, stream>>>(bq, bk, bv, wsb);

  // q,k,v = x @ W + b   (M=16384, N=768, K=768)
  gemm_bt<0><<<dim3(64, 3, 3), 512, 0, stream>>>(
      xb, 0LL, wt, 768LL * 768, qb, nullptr, 16384LL * 768, wsb, 1.0f,
      768, 768, 768, 768);

  transpose_v<<<dim3(24, 64, 8), dim3(32, 8), 0, stream>>>(vb, vt);

  // scores = (q @ k^T) / sqrt(768)  per batch (M=N=2048, K=768)
  gemm_bt<1><<<dim3(8, 8, 8), 512, 0, stream>>>(
      qb, 2048LL * 768, kb, 2048LL * 768, p, nullptr, 2048LL * 2048, nullptr,
      0.03608439182435161f, 768, 768, 2048, 768);

  softmax_rows<<<16384, 256, 0, stream>>>(p);

  // out = p @ v  per batch (M=2048, N=768, K=2048) -> F32 store to d_out
  gemm_bt<2><<<dim3(8, 3, 8), 512, 0, stream>>>(
      p, 2048LL * 2048, vt, 768LL * 2048, nullptr, out, 2048LL * 768, nullptr,
      1.0f, 2048, 2048, 768, 2048);
}

// Round 14
// 298.447 us; speedup vs baseline: 1.0384x; 1.0384x over previous
//
#include <hip/hip_runtime.h>
#include <stdint.h>

typedef unsigned short u16;
typedef __attribute__((ext_vector_type(8))) short short8;
typedef __attribute__((ext_vector_type(4))) float f32x4;
typedef __attribute__((ext_vector_type(8))) u16 u16x8;
typedef __attribute__((ext_vector_type(4))) u16 u16x4;

__device__ __forceinline__ u16 f2bf(float f) {
  union { float f; uint32_t u; } v; v.f = f;
  uint32_t u = v.u;
  uint32_t r = (u + 0x7FFFu + ((u >> 16) & 1u)) >> 16;
  return (u16)r;
}
__device__ __forceinline__ float bf2f(u16 b) {
  union { uint32_t u; float f; } v; v.u = ((uint32_t)b) << 16;
  return v.f;
}

__device__ __forceinline__ void gload16(const u16* g, u16* l) {
  __builtin_amdgcn_global_load_lds(
      (const __attribute__((address_space(1))) void*)g,
      (__attribute__((address_space(3))) void*)l, 16, 0, 0);
}

// C[r][c] = sum_k A[r][k] * Bt[c][k], bf16 in, fp32 accum.
// R14: 256x256 tile, BK=32, 512 thr = 8 waves (2M x 4N), per-wave 128x64,
// FINE 4-phase interleave (m196/m201 style): each phase = {1 quarter-tile
// global_load_lds unit || ds_reads for a later phase || 8 MFMA + setprio},
// 2 barriers/phase, counted vmcnt(1) ONCE per tile (never drains mid-loop).
// LDS = 2 dbuf x 32KB = 64KB static. Swizzle carried (slot ^= (row>>1)&3 on
// source + read; LDS dest linear); for all 4 staging units (row>>1)&3 ==
// (tid>>3)&3, so one source-slot per thread. Oracle-verified epilogue.
// Hazard proof: reads of buf X retire at latest by P2's lgkmcnt(0) of its
// tile; DMA re-targeting X issues only after the NEXT tile's P0 barrier,
// which every wave reaches only after that lgkm wait. Publish of X = P0's
// vmcnt(1) (own loads, in-order) + P0 barrier (cross-wave).
// OMODE 0: +bias, bf16 store (QKV). 1: *scale, bf16 (QK^T). 2: f32 (PV->out).
template<int OMODE>
__global__ __launch_bounds__(512, 2) void gemm_bt(
    const u16* __restrict__ A, long long sAz,
    const u16* __restrict__ Bt, long long sBz,
    u16* __restrict__ C, float* __restrict__ Cf, long long sCz,
    const float* __restrict__ bias, float scale,
    int lda, int ldb, int ldc, int K)
{
  __shared__ __align__(16) u16 As[2][256 * 32];
  __shared__ __align__(16) u16 Bs[2][256 * 32];
  const int tid = threadIdx.x;
  const int w = tid >> 6, l = tid & 63;
  const int wm = w >> 2, wn = w & 3;          // 2 x 4 wave grid
  const int z = blockIdx.z;
  A  += sAz * z;
  Bt += sBz * z;
  const long long czoff = sCz * z;
  const long long bm = (long long)blockIdx.x * 256;
  const long long bn = (long long)blockIdx.y * 256;

  // --- staging: 4 quarter-tile units, 1 gload16/thread each ---
  // uA0: A rows {0-63,128-191}; uA1: +64; uB0: Bt rows {0-31,64-95,128-159,
  // 192-223}; uB1: +32.  (units match phase consumption order)
  const int rowu = tid >> 2;
  const int rA0 = (rowu & 63) | ((rowu & 64) << 1);
  const int rA1 = rA0 + 64;
  const int rB0 = (rowu & 31) | ((rowu & 96) << 1);
  const int rB1 = rB0 + 32;
  const int sst = ((tid & 3) ^ ((tid >> 3) & 3)) * 8;  // pre-swizzled src col
  const u16* pa0 = A  + (bm + rA0) * lda + sst;
  const u16* pa1 = A  + (bm + rA1) * lda + sst;
  const u16* pb0 = Bt + (bn + rB0) * ldb + sst;
  const u16* pb1 = Bt + (bn + rB1) * ldb + sst;
  const int dA0 = rA0 * 32 + (tid & 3) * 8;   // LDS elem offsets (linear dest)
  const int dA1 = rA1 * 32 + (tid & 3) * 8;
  const int dB0 = rB0 * 32 + (tid & 3) * 8;
  const int dB1 = rB1 * 32 + (tid & 3) * 8;

  // --- read offsets: physical slot = logical(l>>4) ^ ((row>>1)&3) ---
  const int slot = ((l >> 4) ^ (((l & 15) >> 1) & 3)) * 8;
  int a_off[8], b_off[4];
#pragma unroll
  for (int r = 0; r < 8; ++r)
    a_off[r] = (wm * 128 + r * 16 + (l & 15)) * 32 + slot;
#pragma unroll
  for (int c = 0; c < 4; ++c)
    b_off[c] = (wn * 64 + c * 16 + (l & 15)) * 32 + slot;

  const int nk = K >> 5;

  // prologue: stage tile 0 into buf 0 (4 loads outstanding; no drain)
  gload16(pa0, &As[0][dA0]); gload16(pb0, &Bs[0][dB0]);
  gload16(pa1, &As[0][dA1]); gload16(pb1, &Bs[0][dB1]);
  pa0 += 32; pa1 += 32; pb0 += 32; pb1 += 32;

  f32x4 acc[8][4] = {};

  for (int t = 0; t < nk; ++t) {
    const int cb = t & 1;
    u16* Anx = &As[cb ^ 1][0];
    u16* Bnx = &Bs[cb ^ 1][0];
    const bool stg = (t + 1 < nk);
    short8 af[4], af2[4], bf[4];
    // ---- P0: publish cur; read bf0-3,af0-3; MFMA r0-3 x c0-1 ----
    if (stg) gload16(pa0, Anx + dA0);
    if (stg) asm volatile("s_waitcnt vmcnt(1)" ::: "memory");
    else     asm volatile("s_waitcnt vmcnt(0)" ::: "memory");
    __builtin_amdgcn_s_barrier();
    __builtin_amdgcn_sched_barrier(0);
#pragma unroll
    for (int c = 0; c < 4; ++c)
      bf[c] = *(const short8*)(&Bs[cb][b_off[c]]);
#pragma unroll
    for (int j = 0; j < 4; ++j)
      af[j] = *(const short8*)(&As[cb][a_off[j]]);
    asm volatile("s_waitcnt lgkmcnt(0)" ::: "memory");
    __builtin_amdgcn_sched_barrier(0);
    __builtin_amdgcn_s_setprio(1);
#pragma unroll
    for (int j = 0; j < 4; ++j)
#pragma unroll
      for (int c = 0; c < 2; ++c)
        acc[j][c] = __builtin_amdgcn_mfma_f32_16x16x32_bf16(
            af[j], bf[c], acc[j][c], 0, 0, 0);
    __builtin_amdgcn_s_setprio(0);
    __builtin_amdgcn_s_barrier();
    __builtin_amdgcn_sched_barrier(0);
    // ---- P1: issue af2 reads (overlap); MFMA r0-3 x c2-3 ----
    if (stg) gload16(pb0, Bnx + dB0);
#pragma unroll
    for (int j = 0; j < 4; ++j)
      af2[j] = *(const short8*)(&As[cb][a_off[4 + j]]);
    __builtin_amdgcn_s_setprio(1);
#pragma unroll
    for (int j = 0; j < 4; ++j)
#pragma unroll
      for (int c = 2; c < 4; ++c)
        acc[j][c] = __builtin_amdgcn_mfma_f32_16x16x32_bf16(
            af[j], bf[c], acc[j][c], 0, 0, 0);
    __builtin_amdgcn_s_setprio(0);
    __builtin_amdgcn_s_barrier();
    __builtin_amdgcn_sched_barrier(0);
    // ---- P2: wait af2; MFMA r4-7 x c0-1 ----
    if (stg) gload16(pa1, Anx + dA1);
    asm volatile("s_waitcnt lgkmcnt(0)" ::: "memory");
    __builtin_amdgcn_sched_barrier(0);
    __builtin_amdgcn_s_setprio(1);
#pragma unroll
    for (int j = 0; j < 4; ++j)
#pragma unroll
      for (int c = 0; c < 2; ++c)
        acc[4 + j][c] = __builtin_amdgcn_mfma_f32_16x16x32_bf16(
            af2[j], bf[c], acc[4 + j][c], 0, 0, 0);
    __builtin_amdgcn_s_setprio(0);
    __builtin_amdgcn_s_barrier();
    __builtin_amdgcn_sched_barrier(0);
    // ---- P3: MFMA r4-7 x c2-3 (register-only) ----
    if (stg) {
      gload16(pb1, Bnx + dB1);
      pa0 += 32; pa1 += 32; pb0 += 32; pb1 += 32;
    }
    __builtin_amdgcn_s_setprio(1);
#pragma unroll
    for (int j = 0; j < 4; ++j)
#pragma unroll
      for (int c = 2; c < 4; ++c)
        acc[4 + j][c] = __builtin_amdgcn_mfma_f32_16x16x32_bf16(
            af2[j], bf[c], acc[4 + j][c], 0, 0, 0);
    __builtin_amdgcn_s_setprio(0);
    __builtin_amdgcn_s_barrier();
    __builtin_amdgcn_sched_barrier(0);
  }

  // epilogue: D col = lane&15, row = (lane>>4)*4 + i  [oracle-verified R7]
#pragma unroll
  for (int r = 0; r < 8; ++r) {
#pragma unroll
    for (int c = 0; c < 4; ++c) {
      const long long rr = bm + wm * 128 + r * 16 + (l >> 4) * 4;
      const long long cc = bn + wn * 64 + c * 16 + (l & 15);
      float badd = 0.f;
      if (OMODE == 0) badd = bias[(long long)z * ldc + cc];
#pragma unroll
      for (int i = 0; i < 4; ++i) {
        float v = acc[r][c][i];
        if (OMODE == 0) v += badd;
        if (OMODE == 1) v *= scale;
        if (OMODE == 2)
          Cf[czoff + (rr + i) * ldc + cc] = v;        // f32 output
        else
          C[czoff + (rr + i) * ldc + cc] = f2bf(v);   // bf16 intermediate
      }
    }
  }
}

// f32 -> bf16, 4 elems/thread, grid-stride
__global__ __launch_bounds__(256) void cvt_f32_bf16(
    const float* __restrict__ src, u16* __restrict__ dst, int n4)
{
  int i = blockIdx.x * 256 + threadIdx.x;
  const int stride = gridDim.x * 256;
  for (; i < n4; i += stride) {
    f32x4 v = *(const f32x4*)(src + (long long)i * 4);
    u16x4 o;
    o[0] = f2bf(v[0]); o[1] = f2bf(v[1]);
    o[2] = f2bf(v[2]); o[3] = f2bf(v[3]);
    *(u16x4*)(dst + (long long)i * 4) = o;
  }
}

// vb [8][2048][768] bf16 -> vt [8][768][2048] bf16
__global__ void transpose_v(const u16* __restrict__ vb, u16* __restrict__ vt)
{
  __shared__ u16 tile[32][33];
  const int b = blockIdx.z;
  const int e0 = blockIdx.x * 32, m0 = blockIdx.y * 32;
  const int tx = threadIdx.x, ty = threadIdx.y;
  const u16* src = vb + ((long long)b * 2048 + m0) * 768 + e0;
#pragma unroll
  for (int i = 0; i < 4; ++i)
    tile[ty + i * 8][tx] = src[(ty + i * 8) * 768 + tx];
  __syncthreads();
  u16* dst = vt + ((long long)b * 768 + e0) * 2048 + m0;
#pragma unroll
  for (int i = 0; i < 4; ++i)
    dst[(ty + i * 8) * 2048 + tx] = tile[tx][ty + i * 8];
}

// W f32 [d][e] -> wt bf16 [z][e][d]
__global__ void prep_w(const float* __restrict__ Wq, const float* __restrict__ Wk,
                       const float* __restrict__ Wv, u16* __restrict__ wt)
{
  __shared__ float tile[32][33];
  const int zz = blockIdx.z;
  const float* W = zz == 0 ? Wq : (zz == 1 ? Wk : Wv);
  const int e0 = blockIdx.x * 32, d0 = blockIdx.y * 32;
  const int tx = threadIdx.x, ty = threadIdx.y;
#pragma unroll
  for (int i = 0; i < 4; ++i)
    tile[ty + i * 8][tx] = W[(long long)(d0 + ty + i * 8) * 768 + e0 + tx];
  __syncthreads();
  u16* dst = wt + (long long)zz * 768 * 768;
#pragma unroll
  for (int i = 0; i < 4; ++i)
    dst[(long long)(e0 + ty + i * 8) * 768 + d0 + tx] = f2bf(tile[tx][ty + i * 8]);
}

// biases f32: pack into contiguous [3][768]
__global__ void prep_b(const float* bq, const float* bk, const float* bv, float* dst)
{
  const int zz = blockIdx.x;
  const float* s = zz == 0 ? bq : (zz == 1 ? bk : bv);
  for (int i = threadIdx.x; i < 768; i += 256) dst[zz * 768 + i] = s[i];
}

// in-place row softmax on bf16 [rows][2048]; one block (256 thr) per row
__global__ __launch_bounds__(256) void softmax_rows(u16* __restrict__ p)
{
  const long long row = blockIdx.x;
  u16* r = p + row * 2048;
  const int t = threadIdx.x;
  const int l = t & 63, w = t >> 6;
  u16x8 vv = *(const u16x8*)(r + t * 8);
  float x[8];
#pragma unroll
  for (int i = 0; i < 8; ++i) x[i] = bf2f(vv[i]);
  float m = x[0];
#pragma unroll
  for (int i = 1; i < 8; ++i) m = fmaxf(m, x[i]);
#pragma unroll
  for (int off = 32; off >= 1; off >>= 1) m = fmaxf(m, __shfl_xor(m, off, 64));
  __shared__ float redm[4], reds[4];
  if (l == 0) redm[w] = m;
  __syncthreads();
  m = fmaxf(fmaxf(redm[0], redm[1]), fmaxf(redm[2], redm[3]));
  float s = 0.f;
#pragma unroll
  for (int i = 0; i < 8; ++i) { x[i] = expf(x[i] - m); s += x[i]; }
#pragma unroll
  for (int off = 32; off >= 1; off >>= 1) s += __shfl_xor(s, off, 64);
  if (l == 0) reds[w] = s;
  __syncthreads();
  s = reds[0] + reds[1] + reds[2] + reds[3];
  const float inv = 1.0f / s;
  u16x8 ov;
#pragma unroll
  for (int i = 0; i < 8; ++i) ov[i] = f2bf(x[i] * inv);
  *(u16x8*)(r + t * 8) = ov;
}

extern "C" void kernel_launch(void* const* d_in, const int* in_sizes, int n_in,
                              void* d_out, int out_size, void* d_ws, size_t ws_size,
                              hipStream_t stream)
{
  (void)in_sizes; (void)n_in; (void)out_size;
  const float* x  = (const float*)d_in[0];
  const float* Wq = (const float*)d_in[1];
  const float* bq = (const float*)d_in[2];
  const float* Wk = (const float*)d_in[3];
  const float* bk = (const float*)d_in[4];
  const float* Wv = (const float*)d_in[5];
  const float* bv = (const float*)d_in[6];
  float* out = (float*)d_out;   // reference output dtype = float32

  // ws layout (bytes): wt @0; qb @3538944; kb,vb follow; vt @79036416;
  // p @104202240 (xb aliased); wsb @171311104. total 171,320,320.
  const size_t NEEDED = 171320320;
  if (ws_size < NEEDED) return;

  char* ws = (char*)d_ws;
  u16* wt  = (u16*)ws;
  u16* qb  = (u16*)(ws + 3538944);
  u16* vt  = (u16*)(ws + 79036416);
  u16* p   = (u16*)(ws + 104202240);
  u16* xb  = p;  // alias: x(bf16) dead before QK^T writes p
  float* wsb = (float*)(ws + 171311104);
  u16* kb = qb + (long long)16384 * 768;
  u16* vb = kb + (long long)16384 * 768;

  cvt_f32_bf16<<<4096, 256, 0, stream>>>(x, xb, 3145728);
  prep_w<<<dim3(24, 24, 3), dim3(32, 8), 0, stream>>>(Wq, Wk, Wv, wt);
  prep_b<<<3, 256, 0, stream>>>(bq, bk, bv, wsb);

  // q,k,v = x @ W + b   (M=16384, N=768, K=768)
  gemm_bt<0><<<dim3(64, 3, 3), 512, 0, stream>>>(
      xb, 0LL, wt, 768LL * 768, qb, nullptr, 16384LL * 768, wsb, 1.0f,
      768, 768, 768, 768);

  transpose_v<<<dim3(24, 64, 8), dim3(32, 8), 0, stream>>>(vb, vt);

  // scores = (q @ k^T) / sqrt(768)  per batch (M=N=2048, K=768)
  gemm_bt<1><<<dim3(8, 8, 8), 512, 0, stream>>>(
      qb, 2048LL * 768, kb, 2048LL * 768, p, nullptr, 2048LL * 2048, nullptr,
      0.03608439182435161f, 768, 768, 2048, 768);

  softmax_rows<<<16384, 256, 0, stream>>>(p);

  // out = p @ v  per batch (M=2048, N=768, K=2048) -> F32 store to d_out
  gemm_bt<2><<<dim3(8, 3, 8), 512, 0, stream>>>(
      p, 2048LL * 2048, vt, 768LL * 2048, nullptr, out, 2048LL * 768, nullptr,
      1.0f, 2048, 2048, 768, 2048);
}

// Round 15
// 238.982 us; speedup vs baseline: 1.2968x; 1.2488x over previous
//
#include <hip/hip_runtime.h>
#include <stdint.h>

typedef unsigned short u16;
typedef __attribute__((ext_vector_type(8))) short short8;
typedef __attribute__((ext_vector_type(4))) float f32x4;
typedef __attribute__((ext_vector_type(8))) u16 u16x8;
typedef __attribute__((ext_vector_type(4))) u16 u16x4;

__device__ __forceinline__ u16 f2bf(float f) {
  union { float f; uint32_t u; } v; v.f = f;
  uint32_t u = v.u;
  uint32_t r = (u + 0x7FFFu + ((u >> 16) & 1u)) >> 16;
  return (u16)r;
}
__device__ __forceinline__ float bf2f(u16 b) {
  union { uint32_t u; float f; } v; v.u = ((uint32_t)b) << 16;
  return v.f;
}

__device__ __forceinline__ void gload16(const u16* g, u16* l) {
  __builtin_amdgcn_global_load_lds(
      (const __attribute__((address_space(1))) void*)g,
      (__attribute__((address_space(3))) void*)l, 16, 0, 0);
}

#define SB0() __builtin_amdgcn_sched_barrier(0)

// C[r][c] = sum_k A[r][k] * Bt[c][k], bf16 in, fp32 accum.
// R15: m201-style 256x256, BK=64, 512 thr = 8 waves (2M x 4N), per-wave
// 128x64 (acc[8][4]). LDS dynamic 128KB: [2 dbuf][2 half][2 kk][128][32]
// per operand (kk-planes keep the R10-proven zero-conflict swizzle).
// Per K64-tile: ONE barrier + vmcnt(0) at boundary (loads led by 5-8 fine
// phases), then 8 phases {stage-half || ds_read quadrant || 8 MFMA+setprio}.
// Halves staged: hA0,hB0 post-barrier/ph0, hA1 ph1, hB1 ph2 (lead >=5 ph).
// OMODE 0: +bias, bf16 store (QKV). 1: *scale, bf16 (QK^T). 2: f32 (PV->out).
template<int OMODE>
__global__ __launch_bounds__(512, 2) void gemm_bt(
    const u16* __restrict__ A, long long sAz,
    const u16* __restrict__ Bt, long long sBz,
    u16* __restrict__ C, float* __restrict__ Cf, long long sCz,
    const float* __restrict__ bias, float scale,
    int lda, int ldb, int ldc, int K)
{
  extern __shared__ __align__(16) u16 smem[];
  u16* As = smem;               // planes: (db*4 + h*2 + kk)*4096 elems
  u16* Bs = smem + 32768;       // same layout
  const int tid = threadIdx.x;
  const int w = tid >> 6, l = tid & 63;
  const int wm = w >> 2, wn = w & 3;          // 2 x 4 wave grid
  const int z = blockIdx.z;
  A  += sAz * z;
  Bt += sBz * z;
  const long long czoff = sCz * z;
  const long long bm = (long long)blockIdx.x * 256;
  const long long bn = (long long)blockIdx.y * 256;

  // --- staging: per half (128 rows x 64k = 16KB) 2 loads/thread (kk0,kk1).
  // thread t: row = t>>2, dest chunk t (linear, = uniform + lane*16B),
  // source slot pre-swizzled: (t&3) ^ ((row>>1)&3), row>>1&3 == (t>>3)&3.
  const int trow = tid >> 2;
  const int tsl = ((tid & 3) ^ ((tid >> 3) & 3)) * 8;
  const u16* pA0 = A  + (bm + trow) * lda + tsl;         // A half0
  const u16* pA1 = A  + (bm + 128 + trow) * lda + tsl;   // A half1
  const u16* pB0 = Bt + (bn + trow) * ldb + tsl;         // B half0
  const u16* pB1 = Bt + (bn + 128 + trow) * ldb + tsl;   // B half1
  const int dst8 = tid * 8;

  // --- read offsets (within a kk-plane, R10-proven swizzle) ---
  const int slot = ((l >> 4) ^ (((l & 15) >> 1) & 3)) * 8;
  int al[8], bl[4];
#pragma unroll
  for (int r = 0; r < 8; ++r)
    al[r] = (r * 16 + (l & 15)) * 32 + slot;      // local row in half
#pragma unroll
  for (int c = 0; c < 4; ++c)
    bl[c] = ((wn & 1) * 64 + c * 16 + (l & 15)) * 32 + slot;

  const int nk = K >> 6;   // K64 tiles

  // prologue: stage tile 0 (4 halves, 8 loads) into db=0
  gload16(pA0,      As + 0 * 4096 + dst8);
  gload16(pA0 + 32, As + 1 * 4096 + dst8);
  gload16(pB0,      Bs + 0 * 4096 + dst8);
  gload16(pB0 + 32, Bs + 1 * 4096 + dst8);
  gload16(pA1,      As + 2 * 4096 + dst8);
  gload16(pA1 + 32, As + 3 * 4096 + dst8);
  gload16(pB1,      Bs + 2 * 4096 + dst8);
  gload16(pB1 + 32, Bs + 3 * 4096 + dst8);
  pA0 += 64; pA1 += 64; pB0 += 64; pB1 += 64;

  f32x4 acc[8][4] = {};

#define MM8(R, CC, AF, BF)                                        \
  __builtin_amdgcn_s_setprio(1);                                  \
  _Pragma("unroll")                                               \
  for (int j = 0; j < 4; ++j)                                     \
    _Pragma("unroll")                                             \
    for (int q = 0; q < 2; ++q)                                   \
      acc[(R) + j][(CC) + q] = __builtin_amdgcn_mfma_f32_16x16x32_bf16( \
          AF[j], BF[q], acc[(R) + j][(CC) + q], 0, 0, 0);         \
  __builtin_amdgcn_s_setprio(0);

  for (int t = 0; t < nk; ++t) {
    asm volatile("s_waitcnt vmcnt(0)" ::: "memory");
    __builtin_amdgcn_s_barrier();
    SB0();
    const int db = (t & 1) * 4;
    const int dn = ((t + 1) & 1) * 4;
    const bool stg = (t + 1 < nk);
    const int paK = db + wm * 2;              // A plane (kk0) for this wave
    const int pbK = db + (wn >> 1) * 2;       // B plane (kk0)
    short8 afA[4], afB[4], bf0[2], bf1[2];
    // -- stage hA0, hB0 (post-barrier: all waves done reading buf dn) --
    if (stg) {
      gload16(pA0,      As + (dn + 0) * 4096 + dst8);
      gload16(pA0 + 32, As + (dn + 1) * 4096 + dst8);
      gload16(pB0,      Bs + (dn + 0) * 4096 + dst8);
      gload16(pB0 + 32, Bs + (dn + 1) * 4096 + dst8);
    }
    // ---- ph0: af r0-3 k0, bf c0-1 k0; MFMA r0-3 x c0-1 ----
#pragma unroll
    for (int j = 0; j < 4; ++j)
      afA[j] = *(const short8*)(As + paK * 4096 + al[j]);
#pragma unroll
    for (int q = 0; q < 2; ++q)
      bf0[q] = *(const short8*)(Bs + pbK * 4096 + bl[q]);
    SB0();
    MM8(0, 0, afA, bf0);
    SB0();
    // ---- ph1: stage hA1; bf c2-3 k0; MFMA r0-3 x c2-3 ----
    if (stg) {
      gload16(pA1,      As + (dn + 2) * 4096 + dst8);
      gload16(pA1 + 32, As + (dn + 3) * 4096 + dst8);
    }
#pragma unroll
    for (int q = 0; q < 2; ++q)
      bf1[q] = *(const short8*)(Bs + pbK * 4096 + bl[2 + q]);
    SB0();
    MM8(0, 2, afA, bf1);
    SB0();
    // ---- ph2: stage hB1; af r4-7 k0; MFMA r4-7 x c2-3 ----
    if (stg) {
      gload16(pB1,      Bs + (dn + 2) * 4096 + dst8);
      gload16(pB1 + 32, Bs + (dn + 3) * 4096 + dst8);
      pA0 += 64; pA1 += 64; pB0 += 64; pB1 += 64;
    }
#pragma unroll
    for (int j = 0; j < 4; ++j)
      afB[j] = *(const short8*)(As + paK * 4096 + al[4 + j]);
    SB0();
    MM8(4, 2, afB, bf1);
    SB0();
    // ---- ph3: MFMA r4-7 x c0-1 (register-only) ----
    MM8(4, 0, afB, bf0);
    SB0();
    // ---- k-half 1 (planes +1) ----
    // ph4: af r0-3 k1, bf c0-1 k1; MFMA r0-3 x c0-1
#pragma unroll
    for (int j = 0; j < 4; ++j)
      afA[j] = *(const short8*)(As + (paK + 1) * 4096 + al[j]);
#pragma unroll
    for (int q = 0; q < 2; ++q)
      bf0[q] = *(const short8*)(Bs + (pbK + 1) * 4096 + bl[q]);
    SB0();
    MM8(0, 0, afA, bf0);
    SB0();
    // ph5: bf c2-3 k1; MFMA r0-3 x c2-3
#pragma unroll
    for (int q = 0; q < 2; ++q)
      bf1[q] = *(const short8*)(Bs + (pbK + 1) * 4096 + bl[2 + q]);
    SB0();
    MM8(0, 2, afA, bf1);
    SB0();
    // ph6: af r4-7 k1; MFMA r4-7 x c2-3
#pragma unroll
    for (int j = 0; j < 4; ++j)
      afB[j] = *(const short8*)(As + (paK + 1) * 4096 + al[4 + j]);
    SB0();
    MM8(4, 2, afB, bf1);
    SB0();
    // ph7: MFMA r4-7 x c0-1
    MM8(4, 0, afB, bf0);
    SB0();
  }
#undef MM8

  // epilogue: D col = lane&15, row = (lane>>4)*4 + i  [oracle-verified R7]
#pragma unroll
  for (int r = 0; r < 8; ++r) {
#pragma unroll
    for (int c = 0; c < 4; ++c) {
      const long long rr = bm + wm * 128 + r * 16 + (l >> 4) * 4;
      const long long cc = bn + wn * 64 + c * 16 + (l & 15);
      float badd = 0.f;
      if (OMODE == 0) badd = bias[(long long)z * ldc + cc];
#pragma unroll
      for (int i = 0; i < 4; ++i) {
        float v = acc[r][c][i];
        if (OMODE == 0) v += badd;
        if (OMODE == 1) v *= scale;
        if (OMODE == 2)
          Cf[czoff + (rr + i) * ldc + cc] = v;        // f32 output
        else
          C[czoff + (rr + i) * ldc + cc] = f2bf(v);   // bf16 intermediate
      }
    }
  }
}

// f32 -> bf16, 4 elems/thread, grid-stride
__global__ __launch_bounds__(256) void cvt_f32_bf16(
    const float* __restrict__ src, u16* __restrict__ dst, int n4)
{
  int i = blockIdx.x * 256 + threadIdx.x;
  const int stride = gridDim.x * 256;
  for (; i < n4; i += stride) {
    f32x4 v = *(const f32x4*)(src + (long long)i * 4);
    u16x4 o;
    o[0] = f2bf(v[0]); o[1] = f2bf(v[1]);
    o[2] = f2bf(v[2]); o[3] = f2bf(v[3]);
    *(u16x4*)(dst + (long long)i * 4) = o;
  }
}

// vb [8][2048][768] bf16 -> vt [8][768][2048] bf16
__global__ void transpose_v(const u16* __restrict__ vb, u16* __restrict__ vt)
{
  __shared__ u16 tile[32][33];
  const int b = blockIdx.z;
  const int e0 = blockIdx.x * 32, m0 = blockIdx.y * 32;
  const int tx = threadIdx.x, ty = threadIdx.y;
  const u16* src = vb + ((long long)b * 2048 + m0) * 768 + e0;
#pragma unroll
  for (int i = 0; i < 4; ++i)
    tile[ty + i * 8][tx] = src[(ty + i * 8) * 768 + tx];
  __syncthreads();
  u16* dst = vt + ((long long)b * 768 + e0) * 2048 + m0;
#pragma unroll
  for (int i = 0; i < 4; ++i)
    dst[(ty + i * 8) * 2048 + tx] = tile[tx][ty + i * 8];
}

// W f32 [d][e] -> wt bf16 [z][e][d]
__global__ void prep_w(const float* __restrict__ Wq, const float* __restrict__ Wk,
                       const float* __restrict__ Wv, u16* __restrict__ wt)
{
  __shared__ float tile[32][33];
  const int zz = blockIdx.z;
  const float* W = zz == 0 ? Wq : (zz == 1 ? Wk : Wv);
  const int e0 = blockIdx.x * 32, d0 = blockIdx.y * 32;
  const int tx = threadIdx.x, ty = threadIdx.y;
#pragma unroll
  for (int i = 0; i < 4; ++i)
    tile[ty + i * 8][tx] = W[(long long)(d0 + ty + i * 8) * 768 + e0 + tx];
  __syncthreads();
  u16* dst = wt + (long long)zz * 768 * 768;
#pragma unroll
  for (int i = 0; i < 4; ++i)
    dst[(long long)(e0 + ty + i * 8) * 768 + d0 + tx] = f2bf(tile[tx][ty + i * 8]);
}

// biases f32: pack into contiguous [3][768]
__global__ void prep_b(const float* bq, const float* bk, const float* bv, float* dst)
{
  const int zz = blockIdx.x;
  const float* s = zz == 0 ? bq : (zz == 1 ? bk : bv);
  for (int i = threadIdx.x; i < 768; i += 256) dst[zz * 768 + i] = s[i];
}

// in-place row softmax on bf16 [rows][2048]; one block (256 thr) per row
__global__ __launch_bounds__(256) void softmax_rows(u16* __restrict__ p)
{
  const long long row = blockIdx.x;
  u16* r = p + row * 2048;
  const int t = threadIdx.x;
  const int l = t & 63, w = t >> 6;
  u16x8 vv = *(const u16x8*)(r + t * 8);
  float x[8];
#pragma unroll
  for (int i = 0; i < 8; ++i) x[i] = bf2f(vv[i]);
  float m = x[0];
#pragma unroll
  for (int i = 1; i < 8; ++i) m = fmaxf(m, x[i]);
#pragma unroll
  for (int off = 32; off >= 1; off >>= 1) m = fmaxf(m, __shfl_xor(m, off, 64));
  __shared__ float redm[4], reds[4];
  if (l == 0) redm[w] = m;
  __syncthreads();
  m = fmaxf(fmaxf(redm[0], redm[1]), fmaxf(redm[2], redm[3]));
  float s = 0.f;
#pragma unroll
  for (int i = 0; i < 8; ++i) { x[i] = expf(x[i] - m); s += x[i]; }
#pragma unroll
  for (int off = 32; off >= 1; off >>= 1) s += __shfl_xor(s, off, 64);
  if (l == 0) reds[w] = s;
  __syncthreads();
  s = reds[0] + reds[1] + reds[2] + reds[3];
  const float inv = 1.0f / s;
  u16x8 ov;
#pragma unroll
  for (int i = 0; i < 8; ++i) ov[i] = f2bf(x[i] * inv);
  *(u16x8*)(r + t * 8) = ov;
}

extern "C" void kernel_launch(void* const* d_in, const int* in_sizes, int n_in,
                              void* d_out, int out_size, void* d_ws, size_t ws_size,
                              hipStream_t stream)
{
  (void)in_sizes; (void)n_in; (void)out_size;
  const float* x  = (const float*)d_in[0];
  const float* Wq = (const float*)d_in[1];
  const float* bq = (const float*)d_in[2];
  const float* Wk = (const float*)d_in[3];
  const float* bk = (const float*)d_in[4];
  const float* Wv = (const float*)d_in[5];
  const float* bv = (const float*)d_in[6];
  float* out = (float*)d_out;   // reference output dtype = float32

  // ws layout (bytes): wt @0; qb @3538944; kb,vb follow; vt @79036416;
  // p @104202240 (xb aliased); wsb @171311104. total 171,320,320.
  const size_t NEEDED = 171320320;
  if (ws_size < NEEDED) return;

  char* ws = (char*)d_ws;
  u16* wt  = (u16*)ws;
  u16* qb  = (u16*)(ws + 3538944);
  u16* vt  = (u16*)(ws + 79036416);
  u16* p   = (u16*)(ws + 104202240);
  u16* xb  = p;  // alias: x(bf16) dead before QK^T writes p
  float* wsb = (float*)(ws + 171311104);
  u16* kb = qb + (long long)16384 * 768;
  u16* vb = kb + (long long)16384 * 768;

  // allow 128KB dynamic LDS (idempotent; not a stream op, capture-safe)
  hipFuncSetAttribute((const void*)&gemm_bt<0>,
                      hipFuncAttributeMaxDynamicSharedMemorySize, 131072);
  hipFuncSetAttribute((const void*)&gemm_bt<1>,
                      hipFuncAttributeMaxDynamicSharedMemorySize, 131072);
  hipFuncSetAttribute((const void*)&gemm_bt<2>,
                      hipFuncAttributeMaxDynamicSharedMemorySize, 131072);

  cvt_f32_bf16<<<4096, 256, 0, stream>>>(x, xb, 3145728);
  prep_w<<<dim3(24, 24, 3), dim3(32, 8), 0, stream>>>(Wq, Wk, Wv, wt);
  prep_b<<<3, 256, 0, stream>>>(bq, bk, bv, wsb);

  // q,k,v = x @ W + b   (M=16384, N=768, K=768)
  gemm_bt<0><<<dim3(64, 3, 3), 512, 131072, stream>>>(
      xb, 0LL, wt, 768LL * 768, qb, nullptr, 16384LL * 768, wsb, 1.0f,
      768, 768, 768, 768);

  transpose_v<<<dim3(24, 64, 8), dim3(32, 8), 0, stream>>>(vb, vt);

  // scores = (q @ k^T) / sqrt(768)  per batch (M=N=2048, K=768)
  gemm_bt<1><<<dim3(8, 8, 8), 512, 131072, stream>>>(
      qb, 2048LL * 768, kb, 2048LL * 768, p, nullptr, 2048LL * 2048, nullptr,
      0.03608439182435161f, 768, 768, 2048, 768);

  softmax_rows<<<16384, 256, 0, stream>>>(p);

  // out = p @ v  per batch (M=2048, N=768, K=2048) -> F32 store to d_out
  gemm_bt<2><<<dim3(8, 3, 8), 512, 131072, stream>>>(
      p, 2048LL * 2048, vt, 768LL * 2048, nullptr, out, 2048LL * 768, nullptr,
      1.0f, 2048, 2048, 768, 2048);
}